// Round 1
// baseline (372.858 us; speedup 1.0000x reference)
//
#include <hip/hip_runtime.h>

// Problem constants (match reference)
#define V       32000
#define D       2048
#define B_SZ    4
#define L_SZ    4096
#define T_VIS   256
#define V_STATIC (V + 8)   // 32008

// One block per token row. Block = 256 threads; each thread copies 2 float4
// (512 float4 = 2048 floats per row). Token id is block-uniform -> the source
// selection branch is wave-uniform (no divergence).
__global__ __launch_bounds__(256) void embed_gather_kernel(
    const float* __restrict__ weight,       // (V, D)
    const float* __restrict__ img_tok,      // (2, D)
    const float* __restrict__ pet_tok,      // (2, D)
    const float* __restrict__ reg_tok,      // (2, D)
    const float* __restrict__ tmpl_tok,     // (2, D)
    const float* __restrict__ image_emb,    // (B, T_VIS, D)
    const int*   __restrict__ text,         // (B, L)
    float*       __restrict__ out)          // (B, L, D)
{
    const int row = blockIdx.x;             // [0, B*L)
    const int t   = text[row];              // uniform per block (L1 broadcast)
    const int b   = row >> 12;              // row / L_SZ (L_SZ == 4096)

    const float* src;
    if (t < V) {
        // bulk vocab row (~99.2% of tokens)
        src = weight + (size_t)t * D;
    } else if (t < V_STATIC) {
        // 8 special rows: image/pet/region/template pairs
        const int s = t - V;
        const float* tab = (s < 2) ? img_tok
                         : (s < 4) ? pet_tok
                         : (s < 6) ? reg_tok
                                   : tmpl_tok;
        src = tab + (size_t)(s & 1) * D;
    } else {
        // per-batch visual latent, clamped to [0, T_VIS-1]
        int vi = t - V_STATIC;
        vi = vi < 0 ? 0 : (vi > T_VIS - 1 ? T_VIS - 1 : vi);
        src = image_emb + ((size_t)b * T_VIS + vi) * D;
    }

    const float4* __restrict__ src4 = (const float4*)src;
    float4*       __restrict__ dst4 = (float4*)(out + (size_t)row * D);

    const int tid = threadIdx.x;
    // D/4 = 512 float4 slots; 256 threads -> 2 each, fully coalesced 16B/lane
    float4 a = src4[tid];
    float4 c = src4[tid + 256];
    dst4[tid]       = a;
    dst4[tid + 256] = c;
}

extern "C" void kernel_launch(void* const* d_in, const int* in_sizes, int n_in,
                              void* d_out, int out_size, void* d_ws, size_t ws_size,
                              hipStream_t stream) {
    const float* weight    = (const float*)d_in[0];
    const float* img_tok   = (const float*)d_in[1];
    const float* pet_tok   = (const float*)d_in[2];
    const float* reg_tok   = (const float*)d_in[3];
    const float* tmpl_tok  = (const float*)d_in[4];
    const float* image_emb = (const float*)d_in[5];
    const int*   text      = (const int*)d_in[6];
    float*       out       = (float*)d_out;

    const int n_rows = B_SZ * L_SZ;   // 16384
    embed_gather_kernel<<<n_rows, 256, 0, stream>>>(
        weight, img_tok, pet_tok, reg_tok, tmpl_tok, image_emb, text, out);
}

// Round 3
// 358.620 us; speedup vs baseline: 1.0397x; 1.0397x over previous
//
#include <hip/hip_runtime.h>

// Problem constants (match reference)
#define V       32000
#define D       2048
#define B_SZ    4
#define L_SZ    4096
#define T_VIS   256
#define V_STATIC (V + 8)   // 32008
#define ROWS_PER_BLOCK 4   // 256 threads = 4 waves, one row per wave

// Native clang vector type — accepted by __builtin_nontemporal_store
// (HIP's float4 is a class and is rejected).
typedef float f4 __attribute__((ext_vector_type(4)));

// One WAVE per token row: 64 lanes x 8 float4 = 2048 floats = one D-row.
// 8 independent 16B loads per lane keeps vmcnt depth at 8 (latency hiding on
// the gathered read). Token id is wave-uniform -> uniform branch, scalar path.
// Output is streamed once and never re-read -> nontemporal stores keep L2 free
// for duplicated weight-row reads.
__global__ __launch_bounds__(256) void embed_gather_kernel(
    const float* __restrict__ weight,       // (V, D)
    const float* __restrict__ img_tok,      // (2, D)
    const float* __restrict__ pet_tok,      // (2, D)
    const float* __restrict__ reg_tok,      // (2, D)
    const float* __restrict__ tmpl_tok,     // (2, D)
    const float* __restrict__ image_emb,    // (B, T_VIS, D)
    const int*   __restrict__ text,         // (B, L)
    float*       __restrict__ out)          // (B, L, D)
{
    const int wave = threadIdx.x >> 6;                    // 0..3
    const int lane = threadIdx.x & 63;
    const int row  = blockIdx.x * ROWS_PER_BLOCK + wave;  // [0, B*L)
    const int t    = text[row];   // same addr across wave -> 1 txn, broadcast
    const int b    = row >> 12;   // row / L_SZ (4096)

    const float* src;
    if (t < V) {
        src = weight + (size_t)t * D;                     // ~99.2% of tokens
    } else if (t < V_STATIC) {
        const int s = t - V;
        const float* tab = (s < 2) ? img_tok
                         : (s < 4) ? pet_tok
                         : (s < 6) ? reg_tok
                                   : tmpl_tok;
        src = tab + (size_t)(s & 1) * D;
    } else {
        int vi = t - V_STATIC;
        vi = vi < 0 ? 0 : (vi > T_VIS - 1 ? T_VIS - 1 : vi);
        src = image_emb + ((size_t)b * T_VIS + vi) * D;
    }

    const f4* __restrict__ src4 = (const f4*)src;
    f4*       __restrict__ dst4 = (f4*)(out + (size_t)row * D);

    // 8 independent loads in flight, then 8 nontemporal stores.
    f4 v0 = src4[lane];
    f4 v1 = src4[lane +  64];
    f4 v2 = src4[lane + 128];
    f4 v3 = src4[lane + 192];
    f4 v4 = src4[lane + 256];
    f4 v5 = src4[lane + 320];
    f4 v6 = src4[lane + 384];
    f4 v7 = src4[lane + 448];
    __builtin_nontemporal_store(v0, &dst4[lane]);
    __builtin_nontemporal_store(v1, &dst4[lane +  64]);
    __builtin_nontemporal_store(v2, &dst4[lane + 128]);
    __builtin_nontemporal_store(v3, &dst4[lane + 192]);
    __builtin_nontemporal_store(v4, &dst4[lane + 256]);
    __builtin_nontemporal_store(v5, &dst4[lane + 320]);
    __builtin_nontemporal_store(v6, &dst4[lane + 384]);
    __builtin_nontemporal_store(v7, &dst4[lane + 448]);
}

extern "C" void kernel_launch(void* const* d_in, const int* in_sizes, int n_in,
                              void* d_out, int out_size, void* d_ws, size_t ws_size,
                              hipStream_t stream) {
    const float* weight    = (const float*)d_in[0];
    const float* img_tok   = (const float*)d_in[1];
    const float* pet_tok   = (const float*)d_in[2];
    const float* reg_tok   = (const float*)d_in[3];
    const float* tmpl_tok  = (const float*)d_in[4];
    const float* image_emb = (const float*)d_in[5];
    const int*   text      = (const int*)d_in[6];
    float*       out       = (float*)d_out;

    const int n_rows = B_SZ * L_SZ;                       // 16384
    embed_gather_kernel<<<n_rows / ROWS_PER_BLOCK, 256, 0, stream>>>(
        weight, img_tok, pet_tok, reg_tok, tmpl_tok, image_emb, text, out);
}